// Round 6
// baseline (124.111 us; speedup 1.0000x reference)
//
#include <hip/hip_runtime.h>

namespace {
constexpr int kL0 = 16384;
constexpr int kN1 = 8195;
constexpr int kN2 = 4101;
constexpr int kTS = 512;                 // outputs per wave-tile
constexpr int kTilesPerRow = kL0 / kTS;  // 32
constexpr int kWaves = 2;                // independent wave-tiles per block
constexpr int kThreads = 64 * kWaves;    // 128

// per-tile sizes (exact dependency ranges)
constexpr int SX  = 602;   // xext  [O-42 , O+560)
constexpr int SA1 = 298;   // a1ext [O/2-18, O/2+280)
constexpr int SA2 = 146;   // a2ext [O/4-6 , O/4+140)
constexpr int SA3 = 70;    // a3    [O/8   , O/8+70)

// per-wave LDS region layout (float offsets; all bases even for b64 writes)
constexpr int XE = 0,   XO = 302;        // x even/odd polyphase (301 each + pad)
constexpr int A1E = 604, A1O = 754;      // a1 polyphase (149 each + pad)
constexpr int A2E = 904, A2O = 978;      // a2 polyphase (73 each + pad)
constexpr int S3 = 1052;                 // a3 plain (70)
constexpr int REG = 1124;                // floats per wave region (4496 B)

constexpr float RLc[8] = {
     0.23037781330885523f,  0.7148465705525415f,   0.6308807679295904f,
    -0.02798376941698385f, -0.18703481171888114f,  0.030841381835986965f,
     0.032883011666982945f, -0.010597401785069032f };

// Composite 3-level low-reconstruction bank: low[8q+r] = sum_m W[r][m]*a3[q+m]
struct WT { float w[8][7]; };
constexpr WT make_w() {
    WT W{};
    for (int r = 0; r < 8; ++r) {
        const int r2 = r >> 1, pi = r & 1;
        for (int u = 0; u < 4; ++u) {
            const float cu = RLc[6 + pi - 2 * u];
            const int k = r2 + u, k2 = k >> 1, pk = k & 1;
            for (int s = 0; s < 4; ++s) {
                const float cs = RLc[6 + pk - 2 * s];
                const int j = k2 + s, j2 = j >> 1, pj = j & 1;
                for (int t = 0; t < 4; ++t)
                    W.w[r][j2 + t] += cu * cs * RLc[6 + pj - 2 * t];
            }
        }
    }
    return W;
}

__device__ constexpr float RL[8] = {
     0.23037781330885523f,  0.7148465705525415f,   0.6308807679295904f,
    -0.02798376941698385f, -0.18703481171888114f,  0.030841381835986965f,
     0.032883011666982945f, -0.010597401785069032f };
__device__ constexpr WT W = make_w();
} // namespace

__device__ __forceinline__ int reflect(int g, int N) {
    if (g < 0)  g = -1 - g;
    if (g >= N) g = 2 * N - 1 - g;
    return g;
}

// one DWT output from polyphase arrays: src_ext[2*gl-6+k] taps RL[k]
__device__ __forceinline__ float tap_pp(const float* __restrict__ R,
                                        int Ebase, int Obase, int mh) {
    float s = R[Ebase + mh] * RL[0];
    s = fmaf(R[Obase + mh],     RL[1], s);
    s = fmaf(R[Ebase + mh + 1], RL[2], s);
    s = fmaf(R[Obase + mh + 1], RL[3], s);
    s = fmaf(R[Ebase + mh + 2], RL[4], s);
    s = fmaf(R[Obase + mh + 2], RL[5], s);
    s = fmaf(R[Ebase + mh + 3], RL[6], s);
    s = fmaf(R[Obase + mh + 3], RL[7], s);
    return s;
}

__global__ void __launch_bounds__(kThreads, 8)
wavelet_wave(const float* __restrict__ x, float* __restrict__ out, int rows) {
    __shared__ float lds[kWaves * REG];
    const int lane = threadIdx.x & 63;
    const int wv   = threadIdx.x >> 6;
    float* __restrict__ R = lds + wv * REG;

    const int row  = blockIdx.x >> 4;                 // 16 blocks per row
    const int tile = ((blockIdx.x & 15) << 1) | wv;   // 0..31
    const int O  = tile * kTS;
    const int X0 = O - 42;
    const int A0 = (O >> 1) - 18;
    const int B0 = (O >> 2) - 6;
    const float* __restrict__ xr = x + (size_t)row * kL0;
    const bool edge = (tile == 0) || (tile == kTilesPerRow - 1);

    // ---- stage: x -> xE/xO polyphase ----
    if (!edge) {
        for (int v = lane; v < 150; v += 64) {        // covers x[X0 .. X0+600)
            const int g = X0 + 4 * v;
            const float2 f0 = *reinterpret_cast<const float2*>(xr + g);
            const float2 f1 = *reinterpret_cast<const float2*>(xr + g + 2);
            *reinterpret_cast<float2*>(&R[XE + 2 * v]) = make_float2(f0.x, f1.x);
            *reinterpret_cast<float2*>(&R[XO + 2 * v]) = make_float2(f0.y, f1.y);
        }
        if (lane == 0) { R[XE + 300] = xr[X0 + 600]; R[XO + 300] = xr[X0 + 601]; }
    } else {
        for (int t = lane; t < SX; t += 64) {
            const float v = xr[reflect(X0 + t, kL0)];
            R[((t & 1) ? XO : XE) + (t >> 1)] = v;
        }
    }
    __syncthreads();

    // ---- a1: 298 outputs, R=5 sliding (lane stride 5 -> conflict-free) ----
    {
        const int m0 = 5 * lane;
        const int c  = (m0 < SA1) ? ((SA1 - m0 < 5) ? SA1 - m0 : 5) : 0;
        if (c == 5 && (A0 + m0) >= 0 && (A0 + m0 + 4) < kN1) {
            float e[8], o[8];
            #pragma unroll
            for (int j = 0; j < 8; ++j) { e[j] = R[XE + m0 + j]; o[j] = R[XO + m0 + j]; }
            #pragma unroll
            for (int i = 0; i < 5; ++i) {
                float s = e[i] * RL[0];
                s = fmaf(o[i],     RL[1], s); s = fmaf(e[i + 1], RL[2], s);
                s = fmaf(o[i + 1], RL[3], s); s = fmaf(e[i + 2], RL[4], s);
                s = fmaf(o[i + 2], RL[5], s); s = fmaf(e[i + 3], RL[6], s);
                s = fmaf(o[i + 3], RL[7], s);
                const int m = m0 + i;
                R[((m & 1) ? A1O : A1E) + (m >> 1)] = s;
            }
        } else if (c > 0) {
            for (int i = 0; i < c; ++i) {
                const int m  = m0 + i;
                const int mh = reflect(A0 + m, kN1) - A0;
                const float s = tap_pp(R, XE, XO, mh);
                R[((m & 1) ? A1O : A1E) + (m >> 1)] = s;
            }
        }
    }
    __syncthreads();

    // ---- a2: 146 outputs, R=3 sliding (lane stride 3 -> conflict-free) ----
    {
        const int m0 = 3 * lane;
        const int c  = (m0 < SA2) ? ((SA2 - m0 < 3) ? SA2 - m0 : 3) : 0;
        if (c == 3 && (B0 + m0) >= 0 && (B0 + m0 + 2) < kN2) {
            float e[6], o[6];
            #pragma unroll
            for (int j = 0; j < 6; ++j) { e[j] = R[A1E + m0 + j]; o[j] = R[A1O + m0 + j]; }
            #pragma unroll
            for (int i = 0; i < 3; ++i) {
                float s = e[i] * RL[0];
                s = fmaf(o[i],     RL[1], s); s = fmaf(e[i + 1], RL[2], s);
                s = fmaf(o[i + 1], RL[3], s); s = fmaf(e[i + 2], RL[4], s);
                s = fmaf(o[i + 2], RL[5], s); s = fmaf(e[i + 3], RL[6], s);
                s = fmaf(o[i + 3], RL[7], s);
                const int m = m0 + i;
                R[((m & 1) ? A2O : A2E) + (m >> 1)] = s;
            }
        } else if (c > 0) {
            for (int i = 0; i < c; ++i) {
                const int m  = m0 + i;
                const int mh = reflect(B0 + m, kN2) - B0;
                const float s = tap_pp(R, A1E, A1O, mh);
                R[((m & 1) ? A2O : A2E) + (m >> 1)] = s;
            }
        }
    }
    __syncthreads();

    // ---- a3: 70 outputs (always interior at a3 level; stride-1 lanes) ----
    for (int t = lane; t < SA3; t += 64)
        R[S3 + t] = tap_pp(R, A2E, A2O, t);
    __syncthreads();

    // ---- final: exactly 64 lanes x 8 outputs via W bank; high = x - low ----
    {
        float a[7];
        #pragma unroll
        for (int m = 0; m < 7; ++m) a[m] = R[S3 + lane + m];
        float lo[8];
        #pragma unroll
        for (int r = 0; r < 8; ++r) {
            float s = a[0] * W.w[r][0];
            #pragma unroll
            for (int m = 1; m < 7; ++m) s = fmaf(a[m], W.w[r][m], s);
            lo[r] = s;
        }
        const float4* xr4 = reinterpret_cast<const float4*>(xr + O + 8 * lane);
        const float4 xv0 = xr4[0], xv1 = xr4[1];
        float* __restrict__ lowp  = out + (size_t)row * kL0 + O + 8 * lane;
        float* __restrict__ highp = lowp + (size_t)rows * kL0;
        reinterpret_cast<float4*>(lowp)[0]  = make_float4(lo[0], lo[1], lo[2], lo[3]);
        reinterpret_cast<float4*>(lowp)[1]  = make_float4(lo[4], lo[5], lo[6], lo[7]);
        reinterpret_cast<float4*>(highp)[0] = make_float4(xv0.x - lo[0], xv0.y - lo[1],
                                                          xv0.z - lo[2], xv0.w - lo[3]);
        reinterpret_cast<float4*>(highp)[1] = make_float4(xv1.x - lo[4], xv1.y - lo[5],
                                                          xv1.z - lo[6], xv1.w - lo[7]);
    }
}

extern "C" void kernel_launch(void* const* d_in, const int* in_sizes, int n_in,
                              void* d_out, int out_size, void* d_ws, size_t ws_size,
                              hipStream_t stream) {
    (void)n_in; (void)d_ws; (void)ws_size; (void)out_size;
    const float* x = (const float*)d_in[0];
    float* out = (float*)d_out;
    const int rows = in_sizes[0] / kL0;                         // 2048
    const int blocks = rows * (kTilesPerRow / kWaves);          // 2048*16
    hipLaunchKernelGGL(wavelet_wave, dim3(blocks), dim3(kThreads), 0, stream,
                       x, out, rows);
}

// Round 7
// 107.336 us; speedup vs baseline: 1.1563x; 1.1563x over previous
//
#include <hip/hip_runtime.h>

namespace {
constexpr int kL0 = 16384;
constexpr int kN1 = 8195;
constexpr int kN2 = 4101;
constexpr int kTS = 2048;
constexpr int kThreads = 256;

// sx[t] <-> x[XB + t], XB = O - 44. Needed range t in [2, 2140).
// Interior tiles DMA-stage t in [4, 2308) (over-stage, in-bounds for O<=12288).
constexpr int SXL = 2308;
constexpr int SA1 = 1066;
constexpr int SA2 = 530;
constexpr int SA3 = 262;

constexpr float RLc[8] = {
     0.23037781330885523f,  0.7148465705525415f,   0.6308807679295904f,
    -0.02798376941698385f, -0.18703481171888114f,  0.030841381835986965f,
     0.032883011666982945f, -0.010597401785069032f };

// Composite 3-level low-reconstruction bank: low[8q+r] = sum_m W[r][m]*a3[q+m]
struct WT { float w[8][7]; };
constexpr WT make_w() {
    WT W{};
    for (int r = 0; r < 8; ++r) {
        const int r2 = r >> 1, pi = r & 1;
        for (int u = 0; u < 4; ++u) {
            const float cu = RLc[6 + pi - 2 * u];
            const int k = r2 + u, k2 = k >> 1, pk = k & 1;
            for (int s = 0; s < 4; ++s) {
                const float cs = RLc[6 + pk - 2 * s];
                const int j = k2 + s, j2 = j >> 1, pj = j & 1;
                for (int t = 0; t < 4; ++t)
                    W.w[r][j2 + t] += cu * cs * RLc[6 + pj - 2 * t];
            }
        }
    }
    return W;
}

__device__ constexpr float RL[8] = {
     0.23037781330885523f,  0.7148465705525415f,   0.6308807679295904f,
    -0.02798376941698385f, -0.18703481171888114f,  0.030841381835986965f,
     0.032883011666982945f, -0.010597401785069032f };
__device__ constexpr WT W = make_w();
} // namespace

__device__ __forceinline__ int reflect(int g, int N) {
    if (g < 0)  g = -1 - g;
    if (g >= N) g = 2 * N - 1 - g;
    return g;
}

__device__ __forceinline__ float tap8s(const float* __restrict__ p) {
    float s = p[0] * RL[0];
    s = fmaf(p[1], RL[1], s); s = fmaf(p[2], RL[2], s);
    s = fmaf(p[3], RL[3], s); s = fmaf(p[4], RL[4], s);
    s = fmaf(p[5], RL[5], s); s = fmaf(p[6], RL[6], s);
    s = fmaf(p[7], RL[7], s);
    return s;
}

typedef __attribute__((address_space(1))) const void gvoid_t;
typedef __attribute__((address_space(3))) void lvoid_t;

__global__ void __launch_bounds__(kThreads, 8)
wavelet_tiled(const float* __restrict__ x, float* __restrict__ out, int rows) {
    __shared__ __align__(16) float sx [SXL];     // 2308
    __shared__ __align__(16) float sa1[1068];
    __shared__ __align__(16) float sa2[532];
    __shared__ __align__(16) float sa3[264];

    const int tid  = threadIdx.x;
    const int row  = blockIdx.x >> 3;
    const int tile = blockIdx.x & 7;
    const int O  = tile << 11;
    const int XB = O - 44;
    const int A0 = (O >> 1) - 18;
    const int B0 = (O >> 2) - 6;
    const float* __restrict__ xr = x + (size_t)row * kL0;

    // ---- stage x -> sx ----
    if (tile != 0 && tile != 7) {
        if (tid < 2) sx[2 + tid] = xr[XB + 2 + tid];
        const int wv = tid >> 6, lane = tid & 63;
        for (int c = wv; c < 9; c += 4) {                 // 9 chunks x 1KB DMA
            const int fo = 4 + (c << 8) + (lane << 2);    // float offset, 16B-aligned
            __builtin_amdgcn_global_load_lds((gvoid_t*)(xr + XB + fo),
                                             (lvoid_t*)(&sx[fo]), 16, 0, 0);
        }
    } else {
        const int t0  = (tile == 0) ? 44 : 4;             // 16B-aligned, in-bounds
        const int thi = (tile == 0) ? 2140 : 2092;
        const int Nv  = (thi - t0) >> 2;
        for (int v = tid; v < Nv; v += kThreads) {
            const float4 val = *reinterpret_cast<const float4*>(xr + XB + t0 + 4 * v);
            float2* dst = reinterpret_cast<float2*>(&sx[t0 + 4 * v]);
            dst[0] = make_float2(val.x, val.y);
            dst[1] = make_float2(val.z, val.w);
        }
        for (int t = 2 + tid; t < 2140; t += kThreads)
            if (t < t0 || t >= thi)
                sx[t] = xr[reflect(XB + t, kL0)];
    }
    __syncthreads();

    // ---- a1: 1066 outputs, 4 per pack; window of pack p = sx[8p+2 .. 8p+15] ----
    for (int p = tid; p < 267; p += kThreads) {
        const int m0 = 4 * p;
        if (p < 266 && (A0 + m0) >= 0 && (A0 + m0 + 3) < kN1) {
            const float4 v0 = *reinterpret_cast<const float4*>(&sx[8 * p]);
            const float4 v1 = *reinterpret_cast<const float4*>(&sx[8 * p + 4]);
            const float4 v2 = *reinterpret_cast<const float4*>(&sx[8 * p + 8]);
            const float4 v3 = *reinterpret_cast<const float4*>(&sx[8 * p + 12]);
            const float e[16] = {v0.x, v0.y, v0.z, v0.w, v1.x, v1.y, v1.z, v1.w,
                                 v2.x, v2.y, v2.z, v2.w, v3.x, v3.y, v3.z, v3.w};
            float o[4];
            #pragma unroll
            for (int i = 0; i < 4; ++i) {
                float s = e[2 + 2 * i] * RL[0];
                #pragma unroll
                for (int k = 1; k < 8; ++k) s = fmaf(e[2 + 2 * i + k], RL[k], s);
                o[i] = s;
            }
            *reinterpret_cast<float4*>(&sa1[m0]) = make_float4(o[0], o[1], o[2], o[3]);
        } else {
            const int c = (SA1 - m0 < 4) ? (SA1 - m0) : 4;
            for (int i = 0; i < c; ++i) {
                const int m  = m0 + i;
                const int mh = reflect(A0 + m, kN1) - A0;
                sa1[m] = tap8s(&sx[2 * mh + 2]);
            }
        }
    }
    __syncthreads();

    // ---- a2: 530 outputs, 133 packs; window of pack p = sa1[8p .. 8p+13] ----
    if (tid < 133) {
        const int p = tid, m0 = 4 * p;
        if (p < 132 && (B0 + m0) >= 0 && (B0 + m0 + 3) < kN2) {
            const float4 v0 = *reinterpret_cast<const float4*>(&sa1[8 * p]);
            const float4 v1 = *reinterpret_cast<const float4*>(&sa1[8 * p + 4]);
            const float4 v2 = *reinterpret_cast<const float4*>(&sa1[8 * p + 8]);
            const float4 v3 = *reinterpret_cast<const float4*>(&sa1[8 * p + 12]);
            const float e[16] = {v0.x, v0.y, v0.z, v0.w, v1.x, v1.y, v1.z, v1.w,
                                 v2.x, v2.y, v2.z, v2.w, v3.x, v3.y, v3.z, v3.w};
            float o[4];
            #pragma unroll
            for (int i = 0; i < 4; ++i) {
                float s = e[2 * i] * RL[0];
                #pragma unroll
                for (int k = 1; k < 8; ++k) s = fmaf(e[2 * i + k], RL[k], s);
                o[i] = s;
            }
            *reinterpret_cast<float4*>(&sa2[m0]) = make_float4(o[0], o[1], o[2], o[3]);
        } else {
            const int c = (SA2 - m0 < 4) ? (SA2 - m0) : 4;
            for (int i = 0; i < c; ++i) {
                const int m  = m0 + i;
                const int mh = reflect(B0 + m, kN2) - B0;
                sa2[m] = tap8s(&sa1[2 * mh]);
            }
        }
    }
    __syncthreads();

    // ---- a3: 262 outputs, 66 packs (no reflection at this level) ----
    if (tid < 66) {
        const int p = tid, m0 = 4 * p;
        if (p < 65) {
            const float4 v0 = *reinterpret_cast<const float4*>(&sa2[8 * p]);
            const float4 v1 = *reinterpret_cast<const float4*>(&sa2[8 * p + 4]);
            const float4 v2 = *reinterpret_cast<const float4*>(&sa2[8 * p + 8]);
            const float4 v3 = *reinterpret_cast<const float4*>(&sa2[8 * p + 12]);
            const float e[16] = {v0.x, v0.y, v0.z, v0.w, v1.x, v1.y, v1.z, v1.w,
                                 v2.x, v2.y, v2.z, v2.w, v3.x, v3.y, v3.z, v3.w};
            float o[4];
            #pragma unroll
            for (int i = 0; i < 4; ++i) {
                float s = e[2 * i] * RL[0];
                #pragma unroll
                for (int k = 1; k < 8; ++k) s = fmaf(e[2 * i + k], RL[k], s);
                o[i] = s;
            }
            *reinterpret_cast<float4*>(&sa3[m0]) = make_float4(o[0], o[1], o[2], o[3]);
        } else {
            sa3[260] = tap8s(&sa2[520]);
            sa3[261] = tap8s(&sa2[522]);
        }
    }
    __syncthreads();

    // ---- final: low[8q+r] via W bank; high = x - low ----
    {
        const float4* xr4 = reinterpret_cast<const float4*>(xr + O + 8 * tid);
        const float4 xv0 = xr4[0], xv1 = xr4[1];          // L2-hot re-read
        float a[7];
        #pragma unroll
        for (int m = 0; m < 7; ++m) a[m] = sa3[tid + m];
        float lo[8];
        #pragma unroll
        for (int r = 0; r < 8; ++r) {
            float s = a[0] * W.w[r][0];
            #pragma unroll
            for (int m = 1; m < 7; ++m) s = fmaf(a[m], W.w[r][m], s);
            lo[r] = s;
        }
        float* __restrict__ lowp  = out + (size_t)row * kL0 + O + 8 * tid;
        float* __restrict__ highp = lowp + (size_t)rows * kL0;
        reinterpret_cast<float4*>(lowp)[0]  = make_float4(lo[0], lo[1], lo[2], lo[3]);
        reinterpret_cast<float4*>(lowp)[1]  = make_float4(lo[4], lo[5], lo[6], lo[7]);
        reinterpret_cast<float4*>(highp)[0] = make_float4(xv0.x - lo[0], xv0.y - lo[1],
                                                          xv0.z - lo[2], xv0.w - lo[3]);
        reinterpret_cast<float4*>(highp)[1] = make_float4(xv1.x - lo[4], xv1.y - lo[5],
                                                          xv1.z - lo[6], xv1.w - lo[7]);
    }
}

extern "C" void kernel_launch(void* const* d_in, const int* in_sizes, int n_in,
                              void* d_out, int out_size, void* d_ws, size_t ws_size,
                              hipStream_t stream) {
    (void)n_in; (void)d_ws; (void)ws_size; (void)out_size;
    const float* x = (const float*)d_in[0];
    float* out = (float*)d_out;
    const int rows = in_sizes[0] / kL0;                   // 2048
    const int blocks = rows * 8;                          // 16384
    hipLaunchKernelGGL(wavelet_tiled, dim3(blocks), dim3(kThreads), 0, stream,
                       x, out, rows);
}